// Round 9
// baseline (960.594 us; speedup 1.0000x reference)
//
#include <hip/hip_runtime.h>
#include <math.h>

#define CIN   3
#define DD    32
#define HH    128
#define WW    128
#define COUTC 24
#define HP    126
#define WP    126
#define PLANE (HH * WW)            // 16384

#define NTH     256                // 4 waves = 4 channels per block
#define LDSROW  68                 // floats per staged row (17 float4, 16B-mult)
#define RPC     10                 // input rows per cin (8 out rows + 2)
#define SLICE_F (CIN * RPC * LDSROW)   // 2040 floats per slice buffer
#define NSLOT   (CIN * RPC * 17)   // 510 float4 staging slots

// One depth slice. Slot of conv[j] = j%3. At slice d: S0=d%3 (zeroed, kd=0),
// S1=(d+2)%3 (kd=1 -> conv[d-1]), S2=(d+1)%3 (kd=2 -> completes conv[d-2]).
// Lane computes 8 consecutive cols: 3x ds_read_b128 per (ci,kh) feeds 8
// outputs (13.5 dw/output vs 18 in the 4-col version).
template<int S0, int S1, int S2>
__device__ __forceinline__ void do_slice(
    int d,
    const float* __restrict__ g0, const float* __restrict__ g1, int act1,
    int lo0, int lo1, float4& st0, float4& st1,
    const float (&w)[81],            // wave-uniform -> SGPRs
    float (&ring)[8][3], float (&mn)[8],
    const float* __restrict__ rbase,
    float* __restrict__ lds)
{
  __syncthreads();                        // buf[d&1] fully staged

  if (d + 1 < DD) {                       // next-slice loads: latency hides here
    st0 = *(const float4*)(g0 + (size_t)(d + 1) * PLANE);
    if (act1) st1 = *(const float4*)(g1 + (size_t)(d + 1) * PLANE);
  }

  const float* bp = rbase + (d & 1) * SLICE_F;

  #pragma unroll
  for (int q = 0; q < 8; ++q) ring[q][S0] = 0.0f;

  #pragma unroll
  for (int ci = 0; ci < CIN; ++ci) {
    #pragma unroll
    for (int kh = 0; kh < 3; ++kh) {
      // rows/ci/kh fold into ds_read immediates; 3x b128 (12 dw, 10 used)
      const float* rp = bp + (ci * RPC + kh) * LDSROW;
      float4 a = *(const float4*)rp;
      float4 b = *(const float4*)(rp + 4);
      float4 c = *(const float4*)(rp + 8);
      float p[12] = {a.x, a.y, a.z, a.w, b.x, b.y, b.z, b.w,
                     c.x, c.y, c.z, c.w};
      #pragma unroll
      for (int kw = 0; kw < 3; ++kw) {
        const float wv0 = w[ci * 27 + 0 + kh * 3 + kw];    // kd=0 -> S0
        const float wv1 = w[ci * 27 + 9 + kh * 3 + kw];    // kd=1 -> S1
        const float wv2 = w[ci * 27 + 18 + kh * 3 + kw];   // kd=2 -> S2
        #pragma unroll
        for (int q = 0; q < 8; ++q) {
          const float xv = p[kw + q];
          ring[q][S0] = fmaf(xv, wv0, ring[q][S0]);
          ring[q][S1] = fmaf(xv, wv1, ring[q][S1]);
          ring[q][S2] = fmaf(xv, wv2, ring[q][S2]);
        }
      }
    }
  }

  if (d >= 2) {                           // S2 = completed conv[d-2]
    #pragma unroll
    for (int q = 0; q < 8; ++q) mn[q] = fminf(mn[q], ring[q][S2]);
  }

  if (d + 1 < DD) {
    float* wb = lds + ((d + 1) & 1) * SLICE_F;
    *(float4*)(wb + lo0) = st0;
    if (act1) *(float4*)(wb + lo1) = st1;
  }
}

__global__ void __launch_bounds__(NTH, 2)
conv3d_min_kernel(const float* __restrict__ x,
                  const float* __restrict__ wgt,
                  const float* __restrict__ bias,
                  float* __restrict__ out)
{
  __shared__ __align__(16) float lds[2 * SLICE_F];   // 16.3 KB

  const int t    = threadIdx.x;
  const int lane = t & 63;
  const int wv   = t >> 6;                 // 4 waves, one channel each
  // channel is wave-uniform: force SGPR so weight loads become s_load
  const int ch   = __builtin_amdgcn_readfirstlane(blockIdx.y * 4 + wv);
  const int r    = lane >> 3;              // output row 0..7 in tile
  const int g    = lane & 7;               // col-group (8 cols)
  const int wt   = blockIdx.x & 1;
  const int ht   = blockIdx.x >> 1;        // 16 h-tiles of 8 rows
  const int bb   = blockIdx.z;
  const int hp0  = ht * 8;
  const int w0   = wt * 64;

  // ---- channel weights (wave-uniform -> SGPR file) ----
  float w[81];
  {
    const float* wc = wgt + ch * 81;
    #pragma unroll
    for (int i = 0; i < 81; ++i) w[i] = wc[i];
  }
  const float bval = bias[ch];

  // ---- staging: 510 float4 slots; slot t for all, slot 256+t for t<254 ----
  const int s1   = t + NTH;
  const int act1 = (s1 < NSLOT);
  const int r0 = t / 17,  j0 = t - r0 * 17;
  const int r1 = s1 / 17, j1 = s1 - r1 * 17;
  const int ci0 = r0 / RPC, rr0 = r0 - ci0 * RPC;
  const int ci1 = r1 / RPC, rr1 = r1 - ci1 * RPC;
  int grow0 = hp0 + rr0; grow0 = grow0 > 127 ? 127 : grow0;  // feeds only invalid rows
  int grow1 = hp0 + rr1; grow1 = grow1 > 127 ? 127 : grow1;
  int gc0 = w0 + j0 * 4; gc0 = gc0 > 124 ? 124 : gc0;        // keeps 16B align
  int gc1 = w0 + j1 * 4; gc1 = gc1 > 124 ? 124 : gc1;
  const float* g0 = x + (size_t)(bb * CIN + ci0) * (DD * PLANE) + grow0 * WW + gc0;
  const float* g1 = x + (size_t)(bb * CIN + ci1) * (DD * PLANE) + grow1 * WW + gc1;
  const int lo0 = r0 * LDSROW + j0 * 4;
  const int lo1 = r1 * LDSROW + j1 * 4;

  // lane's LDS read base: its top input row r, col 8g
  const float* rbase = lds + r * LDSROW + g * 8;

  float ring[8][3];
  float mn[8];
  #pragma unroll
  for (int q = 0; q < 8; ++q) {
    mn[q] = INFINITY;
    ring[q][0] = ring[q][1] = ring[q][2] = 0.0f;
  }

  // ---- prologue: stage slice 0 into buffer 0 ----
  float4 st0 = *(const float4*)g0;
  float4 st1 = make_float4(0.f, 0.f, 0.f, 0.f);
  if (act1) st1 = *(const float4*)g1;
  *(float4*)(lds + lo0) = st0;
  if (act1) *(float4*)(lds + lo1) = st1;

  // ---- stream 32 slices; ring slots compile-time (period 3) ----
  for (int d0 = 0; d0 < 30; d0 += 3) {
    do_slice<0,2,1>(d0,     g0, g1, act1, lo0, lo1, st0, st1, w, ring, mn, rbase, lds);
    do_slice<1,0,2>(d0 + 1, g0, g1, act1, lo0, lo1, st0, st1, w, ring, mn, rbase, lds);
    do_slice<2,1,0>(d0 + 2, g0, g1, act1, lo0, lo1, st0, st1, w, ring, mn, rbase, lds);
  }
  do_slice<0,2,1>(30, g0, g1, act1, lo0, lo1, st0, st1, w, ring, mn, rbase, lds);
  do_slice<1,0,2>(31, g0, g1, act1, lo0, lo1, st0, st1, w, ring, mn, rbase, lds);

  // ---- epilogue: bias + store logits (softmax = kernel 2) ----
  const int orow = hp0 + r;
  if (orow < HP) {
    const int ocol = w0 + g * 8;
    float* op = out + ((size_t)(bb * COUTC + ch) * HP + orow) * WP + ocol;
    #pragma unroll
    for (int half = 0; half < 2; ++half) {
      const int oc = ocol + half * 4;
      if (oc + 3 < WP) {
        float4 o = make_float4(mn[half*4+0] + bval, mn[half*4+1] + bval,
                               mn[half*4+2] + bval, mn[half*4+3] + bval);
        *(float4*)(op + half * 4) = o;
      } else {
        #pragma unroll
        for (int cc = 0; cc < 4; ++cc)
          if (oc + cc < WP) op[half*4+cc] = mn[half*4+cc] + bval;
      }
    }
  }
}

// ---- kernel 2: in-place softmax over the 24 channels ----
__global__ void __launch_bounds__(256)
softmax_ch_kernel(float* __restrict__ out)
{
  const int idx = blockIdx.x * 256 + threadIdx.x;
  const int npx = 16 * HP * WP;            // 254016
  if (idx >= npx) return;
  const int b  = idx / (HP * WP);
  const int hw = idx - b * (HP * WP);
  float* p = out + (size_t)b * COUTC * HP * WP + hw;

  float v[COUTC];
  float mx = -INFINITY;
  #pragma unroll
  for (int c = 0; c < COUTC; ++c) {
    v[c] = p[(size_t)c * HP * WP];
    mx = fmaxf(mx, v[c]);
  }
  float s = 0.0f;
  #pragma unroll
  for (int c = 0; c < COUTC; ++c) {
    v[c] = __expf(v[c] - mx);
    s += v[c];
  }
  const float rcp = 1.0f / s;
  #pragma unroll
  for (int c = 0; c < COUTC; ++c)
    p[(size_t)c * HP * WP] = v[c] * rcp;
}

extern "C" void kernel_launch(void* const* d_in, const int* in_sizes, int n_in,
                              void* d_out, int out_size, void* d_ws, size_t ws_size,
                              hipStream_t stream)
{
  const float* x    = (const float*)d_in[0];
  const float* wgt  = (const float*)d_in[1];
  const float* bias = (const float*)d_in[2];
  float* out = (float*)d_out;

  dim3 grid1(32, 6, 16);                   // (wt + 2*ht, ch-group, batch)
  hipLaunchKernelGGL(conv3d_min_kernel, grid1, dim3(NTH), 0, stream,
                     x, wgt, bias, out);

  const int npx = 16 * HP * WP;
  dim3 grid2((npx + 255) / 256);
  hipLaunchKernelGGL(softmax_ch_kernel, grid2, dim3(256), 0, stream, out);
}

// Round 10
// 617.303 us; speedup vs baseline: 1.5561x; 1.5561x over previous
//
#include <hip/hip_runtime.h>
#include <math.h>

#define CIN   3
#define DD    32
#define HH    128
#define WW    128
#define COUTC 24
#define HP    126
#define WP    126
#define PLANE (HH * WW)            // 16384

#define NTH     256                // 4 waves = 4 channels per block
#define LDSROW  68                 // floats per staged row (17 float4)
#define RPC     10                 // input rows per cin (8 out rows + 2)
#define SLICE_F (CIN * RPC * LDSROW)   // 2040 floats per slice buffer
#define NSLOT   (CIN * RPC * 17)   // 510 float4 staging slots

// Apply one input row (6 dwords in p) to output row o with kernel row kh:
// 3 kw x 3 kd x 4 px = 36 FMAs. Weights are wave-uniform (SGPRs).
template<int SA, int SB, int SC>
__device__ __forceinline__ void tap(int o, int kh, int ci,
    const float (&w)[81], const float (&p)[6], float (&ring)[8][3])
{
  #pragma unroll
  for (int kw = 0; kw < 3; ++kw) {
    const float wv0 = w[ci * 27 + 0 + kh * 3 + kw];   // kd=0 -> SA
    const float wv1 = w[ci * 27 + 9 + kh * 3 + kw];   // kd=1 -> SB
    const float wv2 = w[ci * 27 + 18 + kh * 3 + kw];  // kd=2 -> SC
    #pragma unroll
    for (int cc = 0; cc < 4; ++cc) {
      const float xv = p[kw + cc];
      ring[o * 4 + cc][SA] = fmaf(xv, wv0, ring[o * 4 + cc][SA]);
      ring[o * 4 + cc][SB] = fmaf(xv, wv1, ring[o * 4 + cc][SB]);
      ring[o * 4 + cc][SC] = fmaf(xv, wv2, ring[o * 4 + cc][SC]);
    }
  }
}

// One depth slice. Slot of conv[j] = j%3. At slice d: S0=d%3 (zeroed, kd=0),
// S1=(d+2)%3 (kd=1 -> conv[d-1]), S2=(d+1)%3 (kd=2 -> completes conv[d-2]).
// Lane owns 2 output rows x 4 cols: each input row j (4 per ci) is read ONCE
// (b128+b64) and feeds both rows via the o+kh==j pairs -> 9 dw/output.
template<int S0, int S1, int S2>
__device__ __forceinline__ void do_slice(
    int d,
    const float* __restrict__ g0, const float* __restrict__ g1, int act1,
    int lo0, int lo1, float4& st0, float4& st1,
    const float (&w)[81],            // wave-uniform -> SGPRs
    float (&ring)[8][3], float (&mn)[8],
    const float* __restrict__ rbase,
    float* __restrict__ lds)
{
  __syncthreads();                        // buf[d&1] fully staged

  if (d + 1 < DD) {                       // next-slice loads hide under FMAs
    st0 = *(const float4*)(g0 + (size_t)(d + 1) * PLANE);
    if (act1) st1 = *(const float4*)(g1 + (size_t)(d + 1) * PLANE);
  }

  const float* bp = rbase + (d & 1) * SLICE_F;

  #pragma unroll
  for (int q = 0; q < 8; ++q) ring[q][S0] = 0.0f;

  #pragma unroll
  for (int ci = 0; ci < CIN; ++ci) {
    #pragma unroll
    for (int j = 0; j < 4; ++j) {        // input row rbase+j
      const float* rp = bp + (ci * RPC + j) * LDSROW;
      float4 a  = *(const float4*)rp;
      float2 b2 = *(const float2*)(rp + 4);
      float p[6] = {a.x, a.y, a.z, a.w, b2.x, b2.y};
      if (j == 0) { tap<S0,S1,S2>(0, 0, ci, w, p, ring); }
      if (j == 1) { tap<S0,S1,S2>(0, 1, ci, w, p, ring);
                    tap<S0,S1,S2>(1, 0, ci, w, p, ring); }
      if (j == 2) { tap<S0,S1,S2>(0, 2, ci, w, p, ring);
                    tap<S0,S1,S2>(1, 1, ci, w, p, ring); }
      if (j == 3) { tap<S0,S1,S2>(1, 2, ci, w, p, ring); }
    }
  }

  if (d >= 2) {                           // S2 = completed conv[d-2]
    #pragma unroll
    for (int q = 0; q < 8; ++q) mn[q] = fminf(mn[q], ring[q][S2]);
  }

  if (d + 1 < DD) {
    float* wb = lds + ((d + 1) & 1) * SLICE_F;
    *(float4*)(wb + lo0) = st0;
    if (act1) *(float4*)(wb + lo1) = st1;
  }
}

__global__ void __launch_bounds__(NTH, 2)
conv3d_min_kernel(const float* __restrict__ x,
                  const float* __restrict__ wgt,
                  const float* __restrict__ bias,
                  float* __restrict__ out)
{
  __shared__ __align__(16) float lds[2 * SLICE_F];   // 16.3 KB

  const int t    = threadIdx.x;
  const int lane = t & 63;
  const int wv   = t >> 6;                 // 4 waves, one channel each
  // channel is wave-uniform: force SGPR so weight loads become s_load
  const int ch   = __builtin_amdgcn_readfirstlane(blockIdx.y * 4 + wv);
  const int rp_  = lane >> 4;              // row-pair 0..3
  const int g    = lane & 15;              // col-group (4 cols)
  const int rbase_r = rp_ * 2;             // top output row of the pair
  const int wt   = blockIdx.x & 1;
  const int ht   = blockIdx.x >> 1;        // 16 h-tiles of 8 rows
  const int bb   = blockIdx.z;
  const int hp0  = ht * 8;
  const int w0   = wt * 64;

  // ---- channel weights (wave-uniform -> SGPR file) ----
  float w[81];
  {
    const float* wc = wgt + ch * 81;
    #pragma unroll
    for (int i = 0; i < 81; ++i) w[i] = wc[i];
  }
  const float bval = bias[ch];

  // ---- staging: 510 float4 slots; slot t for all, slot 256+t for t<254 ----
  const int s1   = t + NTH;
  const int act1 = (s1 < NSLOT);
  const int r0 = t / 17,  j0 = t - r0 * 17;
  const int r1 = s1 / 17, j1 = s1 - r1 * 17;
  const int ci0 = r0 / RPC, rr0 = r0 - ci0 * RPC;
  const int ci1 = r1 / RPC, rr1 = r1 - ci1 * RPC;
  int grow0 = hp0 + rr0; grow0 = grow0 > 127 ? 127 : grow0;  // feeds only invalid rows
  int grow1 = hp0 + rr1; grow1 = grow1 > 127 ? 127 : grow1;
  int gc0 = w0 + j0 * 4; gc0 = gc0 > 124 ? 124 : gc0;        // keeps 16B align
  int gc1 = w0 + j1 * 4; gc1 = gc1 > 124 ? 124 : gc1;
  const float* g0 = x + (size_t)(bb * CIN + ci0) * (DD * PLANE) + grow0 * WW + gc0;
  const float* g1 = x + (size_t)(bb * CIN + ci1) * (DD * PLANE) + grow1 * WW + gc1;
  const int lo0 = r0 * LDSROW + j0 * 4;
  const int lo1 = r1 * LDSROW + j1 * 4;

  // lane's LDS read base: its top input row, col 4g
  const float* rbase = lds + rbase_r * LDSROW + g * 4;

  float ring[8][3];
  float mn[8];
  #pragma unroll
  for (int q = 0; q < 8; ++q) {
    mn[q] = INFINITY;
    ring[q][0] = ring[q][1] = ring[q][2] = 0.0f;
  }

  // ---- prologue: stage slice 0 into buffer 0 ----
  float4 st0 = *(const float4*)g0;
  float4 st1 = make_float4(0.f, 0.f, 0.f, 0.f);
  if (act1) st1 = *(const float4*)g1;
  *(float4*)(lds + lo0) = st0;
  if (act1) *(float4*)(lds + lo1) = st1;

  // ---- stream 32 slices; ring slots compile-time (period 3) ----
  for (int d0 = 0; d0 < 30; d0 += 3) {
    do_slice<0,2,1>(d0,     g0, g1, act1, lo0, lo1, st0, st1, w, ring, mn, rbase, lds);
    do_slice<1,0,2>(d0 + 1, g0, g1, act1, lo0, lo1, st0, st1, w, ring, mn, rbase, lds);
    do_slice<2,1,0>(d0 + 2, g0, g1, act1, lo0, lo1, st0, st1, w, ring, mn, rbase, lds);
  }
  do_slice<0,2,1>(30, g0, g1, act1, lo0, lo1, st0, st1, w, ring, mn, rbase, lds);
  do_slice<1,0,2>(31, g0, g1, act1, lo0, lo1, st0, st1, w, ring, mn, rbase, lds);

  // ---- epilogue: bias + store logits (softmax = kernel 2) ----
  #pragma unroll
  for (int o = 0; o < 2; ++o) {
    const int orow = hp0 + rbase_r + o;
    if (orow < HP) {
      const int ocol = w0 + g * 4;
      float* op = out + ((size_t)(bb * COUTC + ch) * HP + orow) * WP + ocol;
      if (ocol + 3 < WP) {
        float4 ov = make_float4(mn[o*4+0] + bval, mn[o*4+1] + bval,
                                mn[o*4+2] + bval, mn[o*4+3] + bval);
        *(float4*)op = ov;
      } else {
        #pragma unroll
        for (int cc = 0; cc < 4; ++cc)
          if (ocol + cc < WP) op[cc] = mn[o*4+cc] + bval;
      }
    }
  }
}

// ---- kernel 2: in-place softmax over the 24 channels ----
__global__ void __launch_bounds__(256)
softmax_ch_kernel(float* __restrict__ out)
{
  const int idx = blockIdx.x * 256 + threadIdx.x;
  const int npx = 16 * HP * WP;            // 254016
  if (idx >= npx) return;
  const int b  = idx / (HP * WP);
  const int hw = idx - b * (HP * WP);
  float* p = out + (size_t)b * COUTC * HP * WP + hw;

  float v[COUTC];
  float mx = -INFINITY;
  #pragma unroll
  for (int c = 0; c < COUTC; ++c) {
    v[c] = p[(size_t)c * HP * WP];
    mx = fmaxf(mx, v[c]);
  }
  float s = 0.0f;
  #pragma unroll
  for (int c = 0; c < COUTC; ++c) {
    v[c] = __expf(v[c] - mx);
    s += v[c];
  }
  const float rcp = 1.0f / s;
  #pragma unroll
  for (int c = 0; c < COUTC; ++c)
    p[(size_t)c * HP * WP] = v[c] * rcp;
}

extern "C" void kernel_launch(void* const* d_in, const int* in_sizes, int n_in,
                              void* d_out, int out_size, void* d_ws, size_t ws_size,
                              hipStream_t stream)
{
  const float* x    = (const float*)d_in[0];
  const float* wgt  = (const float*)d_in[1];
  const float* bias = (const float*)d_in[2];
  float* out = (float*)d_out;

  dim3 grid1(32, 6, 16);                   // (wt + 2*ht, ch-group, batch)
  hipLaunchKernelGGL(conv3d_min_kernel, grid1, dim3(NTH), 0, stream,
                     x, wgt, bias, out);

  const int npx = 16 * HP * WP;
  dim3 grid2((npx + 255) / 256);
  hipLaunchKernelGGL(softmax_ch_kernel, grid2, dim3(256), 0, stream, out);
}